// Round 21
// baseline (348.379 us; speedup 1.0000x reference)
//
#include <hip/hip_runtime.h>

// Problem constants
#define NBATCH 8
#define NLQ    256
#define NLK    1024
#define NDQ    512
#define NDV    512
#define NH     128
#define NEGV   -1000000.0f
#define TANH_SCALE 2.8853900817779268f   // 2*log2(e)
#define LOG2E      1.4426950408889634f

using f16x8 = __attribute__((ext_vector_type(8))) _Float16;
using f16x4 = __attribute__((ext_vector_type(4))) _Float16;
using f16x2 = __attribute__((ext_vector_type(2))) _Float16;
using f32x4 = __attribute__((ext_vector_type(4))) float;

__device__ __forceinline__ float fast_exp2(float x) {
#if __has_builtin(__builtin_amdgcn_exp2f)
  return __builtin_amdgcn_exp2f(x);
#else
  return exp2f(x);
#endif
}
__device__ __forceinline__ float fast_rcp(float x) {
#if __has_builtin(__builtin_amdgcn_rcpf)
  return __builtin_amdgcn_rcpf(x);
#else
  return 1.0f / x;
#endif
}

// ---------------------------------------------------------------------------
// Prep: WT fp16 [2][128][512]; WT[s][n][k] = W_s[k][n]. 256 KB, L2-resident.
// ---------------------------------------------------------------------------
__global__ __launch_bounds__(256)
void prep_wT_kernel(const float* __restrict__ Wq, const float* __restrict__ Wk,
                    _Float16* __restrict__ wT) {
  const int idx = blockIdx.x * 256 + threadIdx.x;   // 0 .. 2*512*128-1
  const int n = idx & 127;
  const int k = (idx >> 7) & 511;
  const int s = idx >> 16;
  const float* W = s ? Wk : Wq;
  wT[((size_t)(s * NH + n)) * NDQ + k] = (_Float16)W[k * NH + n];
}

// ---------------------------------------------------------------------------
// Projections via fp16 MFMA, LDS-FREE, barrier-free.
// Wave = 16 rows x 32 cols (2 frags of 16x16), block = 4 waves (64 rows).
// Grid (160, 4): bx<32 -> Q (M=2048), else K (M=8192); by = n-quarter.
// vlen-skip: K-blocks whose 64 keys all lie >= vlen[b] return immediately.
// Epilogue: exp2(acc*2log2e); Q -> Eq fp32 row-major;
// K -> ekC16 fp16 [b][h/8][key][8] (8 h-values contiguous per key;
// saturation-correct: Ek inf -> rcp 0 = tanh->1; Ek 0 -> rcp 1 = tanh->-1).
// ---------------------------------------------------------------------------
__global__ __launch_bounds__(256)
void proj_mfma_kernel(const float* __restrict__ Q, const float* __restrict__ Kin,
                      const _Float16* __restrict__ wT, const int* __restrict__ vlen,
                      float* __restrict__ qp, _Float16* __restrict__ ekC16) {
  const int bx = blockIdx.x;
  const int nq = blockIdx.y;          // n-quarter: cols nq*32 .. nq*32+31
  const bool isQ = (bx < 32);
  const float* A = isQ ? Q : Kin;
  const int m0 = (isQ ? bx : bx - 32) * 64;
  const int sIdx = isQ ? 0 : 1;

  if (!isQ) {
    const int b = m0 >> 10;
    if ((m0 & 1023) >= vlen[b]) return;   // dead keys: never consumed unmasked
  }

  const int w = threadIdx.x >> 6, lane = threadIdx.x & 63;
  const int mrow = m0 + w * 16 + (lane & 15);
  const int kseg = (lane >> 4) * 8;

  const float* aBase = A + (size_t)mrow * NDQ + kseg;
  const _Float16* wt0 = wT + ((size_t)(sIdx * NH + nq * 32 +      (lane & 15))) * NDQ + kseg;
  const _Float16* wt1 = wT + ((size_t)(sIdx * NH + nq * 32 + 16 + (lane & 15))) * NDQ + kseg;

  f32x4 acc0 = {}, acc1 = {};
#pragma unroll 4
  for (int k0 = 0; k0 < NDQ; k0 += 32) {
    const float4 a0 = *(const float4*)&aBase[k0];
    const float4 a1 = *(const float4*)&aBase[k0 + 4];
    f16x8 af;
    af[0] = (_Float16)a0.x; af[1] = (_Float16)a0.y;
    af[2] = (_Float16)a0.z; af[3] = (_Float16)a0.w;
    af[4] = (_Float16)a1.x; af[5] = (_Float16)a1.y;
    af[6] = (_Float16)a1.z; af[7] = (_Float16)a1.w;
    const f16x8 b0 = *(const f16x8*)&wt0[k0];
    const f16x8 b1 = *(const f16x8*)&wt1[k0];
    acc0 = __builtin_amdgcn_mfma_f32_16x16x32_f16(af, b0, acc0, 0, 0, 0);
    acc1 = __builtin_amdgcn_mfma_f32_16x16x32_f16(af, b1, acc1, 0, 0, 0);
  }

  const int orow = m0 + w * 16 + (lane >> 4) * 4;   // + r
  const int col0 = nq * 32 + (lane & 15);           // frag0 col; frag1 = +16
  if (isQ) {
#pragma unroll
    for (int r = 0; r < 4; ++r) {
      qp[(size_t)(orow + r) * NH + col0]      = fast_exp2(acc0[r] * TANH_SCALE);
      qp[(size_t)(orow + r) * NH + col0 + 16] = fast_exp2(acc1[r] * TANH_SCALE);
    }
  } else {
#pragma unroll
    for (int r = 0; r < 4; ++r) {
      const int grow = orow + r;
      const int b = grow >> 10, key = grow & 1023;
      const int c0 = col0, c1 = col0 + 16;
      ekC16[(((size_t)b * 16 + (c0 >> 3)) * NLK + key) * 8 + (c0 & 7)] =
          (_Float16)fast_exp2(acc0[r] * TANH_SCALE);
      ekC16[(((size_t)b * 16 + (c1 >> 3)) * NLK + key) * 8 + (c1 & 7)] =
          (_Float16)fast_exp2(acc1[r] * TANH_SCALE);
    }
  }
}

// ---------------------------------------------------------------------------
// FUSED scores + masked softmax -> fp16 attn, v21 (R5-structure revival).
// REGISTER-RESIDENT k: lane owns ONE key; 16x f16x8 (16B coalesced, 1KB/wave)
// BURST-loaded upfront (16-deep queue) = 64 VGPR; the math loop then has
// ZERO memory ops except wave-uniform q/w scalar loads (R5 proved these
// sustain ~73% VALUBusy). Block = 1024 thr = 16 waves = all 1024 keys,
// QR=4; grid (64, NBATCH) = 512 blocks. vlen skip: waves beyond VL skip
// burst + math. In-block softmax across 16 waves via LDS.
//   score = Wsum - 2*sum_h w*rcp(1 + Eq*Ek); Wsum cancels in softmax.
// ---------------------------------------------------------------------------
__global__ __launch_bounds__(1024)
void scores_softmax_kernel(const float* __restrict__ qp, const _Float16* __restrict__ ekC16,
                           const float* __restrict__ wv, const int* __restrict__ vlen,
                           _Float16* __restrict__ attnH) {
  const int qg = blockIdx.x;            // q group (4 rows), 0..63
  const int b  = blockIdx.y;            // batch
  const int w = threadIdx.x >> 6;       // 0..15 -> key segment of 64
  const int lane = threadIdx.x & 63;
  const int key = w * 64 + lane;

  __shared__ float redm[16][4];
  __shared__ float reds[16][4];

  const _Float16* kbase = ekC16 + ((size_t)b * 16 * NLK + key) * 8;  // + c*NLK*8
  const float* qbase = &qp[(size_t)(b * NLQ + qg * 4) * NH];
  const int VL = vlen[b];

  float acc[4] = {};
  if (w * 64 < VL) {                    // wave-uniform: skip fully-masked segments
    // burst: entire key vector (128 h, fp16) into 64 VGPRs; 16 loads in flight
    f16x8 kr[16];
#pragma unroll
    for (int c = 0; c < 16; ++c)
      kr[c] = *(const f16x8*)&kbase[(size_t)c * NLK * 8];

    // pure-compute loop: q/w via wave-uniform scalar loads only
#pragma unroll
    for (int c = 0; c < 16; ++c) {
      const float4 wa = *(const float4*)&wv[c * 8];        // uniform
      const float4 wb = *(const float4*)&wv[c * 8 + 4];    // uniform
      float4 qa[4], qb[4];
#pragma unroll
      for (int qi = 0; qi < 4; ++qi) {
        qa[qi] = *(const float4*)&qbase[qi * NH + c * 8];      // uniform
        qb[qi] = *(const float4*)&qbase[qi * NH + c * 8 + 4];  // uniform
      }
      const float k0 = (float)kr[c][0], k1 = (float)kr[c][1];
      const float k2 = (float)kr[c][2], k3 = (float)kr[c][3];
      const float k4 = (float)kr[c][4], k5 = (float)kr[c][5];
      const float k6 = (float)kr[c][6], k7 = (float)kr[c][7];
#pragma unroll
      for (int qi = 0; qi < 4; ++qi) {
        float a = acc[qi];
        a = fmaf(wa.x, fast_rcp(fmaf(qa[qi].x, k0, 1.0f)), a);
        a = fmaf(wa.y, fast_rcp(fmaf(qa[qi].y, k1, 1.0f)), a);
        a = fmaf(wa.z, fast_rcp(fmaf(qa[qi].z, k2, 1.0f)), a);
        a = fmaf(wa.w, fast_rcp(fmaf(qa[qi].w, k3, 1.0f)), a);
        a = fmaf(wb.x, fast_rcp(fmaf(qb[qi].x, k4, 1.0f)), a);
        a = fmaf(wb.y, fast_rcp(fmaf(qb[qi].y, k5, 1.0f)), a);
        a = fmaf(wb.z, fast_rcp(fmaf(qb[qi].z, k6, 1.0f)), a);
        a = fmaf(wb.w, fast_rcp(fmaf(qb[qi].w, k7, 1.0f)), a);
        acc[qi] = a;
      }
    }
  }

  // finalize scores with mask
  float s[4];
#pragma unroll
  for (int qi = 0; qi < 4; ++qi)
    s[qi] = (key < VL) ? -2.0f * acc[qi] : NEGV;

  // wave-level max per q-row, then cross-wave via LDS
#pragma unroll
  for (int qi = 0; qi < 4; ++qi) {
    float m = s[qi];
#pragma unroll
    for (int off = 32; off > 0; off >>= 1) m = fmaxf(m, __shfl_xor(m, off));
    if (lane == 0) redm[w][qi] = m;
  }
  __syncthreads();
  float mg[4];
#pragma unroll
  for (int qi = 0; qi < 4; ++qi) {
    float m = redm[0][qi];
#pragma unroll
    for (int ww = 1; ww < 16; ++ww) m = fmaxf(m, redm[ww][qi]);
    mg[qi] = m;
  }

  // exp + wave sum + cross-wave sum
  float p[4];
#pragma unroll
  for (int qi = 0; qi < 4; ++qi) {
    p[qi] = fast_exp2((s[qi] - mg[qi]) * LOG2E);
    float sum = p[qi];
#pragma unroll
    for (int off = 32; off > 0; off >>= 1) sum += __shfl_xor(sum, off);
    if (lane == 0) reds[w][qi] = sum;
  }
  __syncthreads();

#pragma unroll
  for (int qi = 0; qi < 4; ++qi) {
    float tot = reds[0][qi];
#pragma unroll
    for (int ww = 1; ww < 16; ++ww) tot += reds[ww][qi];
    const float inv = fast_rcp(tot);
    attnH[(size_t)(b * NLQ + qg * 4 + qi) * NLK + key] = (_Float16)(p[qi] * inv);
  }
}

// ---------------------------------------------------------------------------
// PV via fp16 MFMA: out[b] = attn[b] (256x1024 fp16) @ V[b].
// Tile M64 x N32 -> grid (4,16,8) = 512 blocks = 2 blocks/CU.
// Block 256 thr = 4 waves; K-step 32, register prefetch. vlen-adaptive:
// attn==0 for keys>=VL, K-loop stops at ceil(VL/32)*32.
// ---------------------------------------------------------------------------
__global__ __launch_bounds__(256)
void pv_mfma_kernel(const _Float16* __restrict__ attnH, const float* __restrict__ V,
                    const int* __restrict__ vlen, float* __restrict__ out) {
  const int b  = blockIdx.z;
  const int m0 = blockIdx.x * 64;
  const int n0 = blockIdx.y * 32;
  const int tid = threadIdx.x;
  const int w = tid >> 6, lane = tid & 63;
  const int kmax = (vlen[b] + 31) & ~31;   // ceil to K-step; >=32 since VL>=1

  __shared__ _Float16 aT[64][40];   // [m][k]
  __shared__ _Float16 vT[32][32];   // [n][k], swizzled

  const _Float16* aBase = attnH + (size_t)(b * NLQ + m0) * NLK;
  const float*    vBase = V + (size_t)b * NLK * NDV + n0;
  float*          oBase = out + (size_t)(b * NLQ + m0) * NDV + n0;

  const int ar = tid >> 2;               // 0..63
  const int ak = (tid & 3) * 8;          // 0,8,16,24
  const int vk = tid >> 3;               // 0..31 (k within tile)
  const int vn = (tid & 7) * 4;          // 0..28 (n within tile)
  const int vswz = ((vn >> 2) & 3) << 3;

  const int am  = w * 16 + (lane & 15);
  const int akf = (lane >> 4) * 8;
  const int bn  = lane & 15;
  const int bks = akf ^ (((bn >> 2) & 3) << 3);

  f32x4 acc0 = {}, acc1 = {};

  // prologue: prefetch tile 0 into registers
  f16x8 aReg = *(const f16x8*)&aBase[(size_t)ar * NLK + ak];
  float4 vReg = *(const float4*)&vBase[(size_t)vk * NDV + vn];

  for (int k0 = 0; k0 < kmax; k0 += 32) {
    __syncthreads();   // previous tile's LDS reads complete
    *(f16x8*)&aT[ar][ak] = aReg;
    {
      const int ks = vk ^ vswz;
      vT[vn + 0][ks] = (_Float16)vReg.x;
      vT[vn + 1][ks] = (_Float16)vReg.y;
      vT[vn + 2][ks] = (_Float16)vReg.z;
      vT[vn + 3][ks] = (_Float16)vReg.w;
    }
    __syncthreads();

    // prefetch NEXT tile while current MFMAs run
    if (k0 + 32 < kmax) {
      aReg = *(const f16x8*)&aBase[(size_t)ar * NLK + k0 + 32 + ak];
      vReg = *(const float4*)&vBase[(size_t)(k0 + 32 + vk) * NDV + vn];
    }

    const f16x8 af = *(const f16x8*)&aT[am][akf];
    const f16x8 bf0 = *(const f16x8*)&vT[ 0 + bn][bks];
    const f16x8 bf1 = *(const f16x8*)&vT[16 + bn][bks];
    acc0 = __builtin_amdgcn_mfma_f32_16x16x32_f16(af, bf0, acc0, 0, 0, 0);
    acc1 = __builtin_amdgcn_mfma_f32_16x16x32_f16(af, bf1, acc1, 0, 0, 0);
  }

  const int orow = w * 16 + (lane >> 4) * 4;
  const int ocol = lane & 15;
#pragma unroll
  for (int r = 0; r < 4; ++r) {
    oBase[(size_t)(orow + r) * NDV + ocol +  0] = acc0[r];
    oBase[(size_t)(orow + r) * NDV + ocol + 16] = acc1[r];
  }
}

// ---------------------------------------------------------------------------
extern "C" void kernel_launch(void* const* d_in, const int* in_sizes, int n_in,
                              void* d_out, int out_size, void* d_ws, size_t ws_size,
                              hipStream_t stream) {
  const float* Q    = (const float*)d_in[0];
  const float* Kin  = (const float*)d_in[1];
  const float* V    = (const float*)d_in[2];
  const int*   vlen = (const int*)d_in[3];
  const float* Wq   = (const float*)d_in[4];
  const float* Wk   = (const float*)d_in[5];
  const float* wv   = (const float*)d_in[6];
  float* out = (float*)d_out;

  float* qp = (float*)d_ws;                               // Eq fp32: 2048*128
  _Float16* ekC16 = (_Float16*)(qp + NBATCH * NLQ * NH);  // fp16: 8*16*1024*8
  _Float16* attnH = ekC16 + (size_t)NBATCH * NH * NLK;    // fp16: 8*256*1024
  _Float16* wT = attnH + (size_t)NBATCH * NLQ * NLK;      // fp16: 2*128*512

  hipLaunchKernelGGL(prep_wT_kernel, dim3(2 * NDQ * NH / 256), dim3(256), 0, stream,
                     Wq, Wk, wT);
  hipLaunchKernelGGL(proj_mfma_kernel, dim3(160, 4), dim3(256), 0, stream,
                     Q, Kin, wT, vlen, qp, ekC16);
  hipLaunchKernelGGL(scores_softmax_kernel, dim3(64, NBATCH), dim3(1024), 0, stream,
                     qp, ekC16, wv, vlen, attnH);
  hipLaunchKernelGGL(pv_mfma_kernel, dim3(NLQ / 64, NDV / 32, NBATCH), dim3(256), 0, stream,
                     attnH, V, vlen, out);
}

// Round 22
// 208.162 us; speedup vs baseline: 1.6736x; 1.6736x over previous
//
#include <hip/hip_runtime.h>

// Problem constants
#define NBATCH 8
#define NLQ    256
#define NLK    1024
#define NDQ    512
#define NDV    512
#define NH     128
#define NEGV   -1000000.0f
#define TANH_SCALE 2.8853900817779268f   // 2*log2(e)
#define LOG2E      1.4426950408889634f

using f16x8 = __attribute__((ext_vector_type(8))) _Float16;
using f16x4 = __attribute__((ext_vector_type(4))) _Float16;
using f16x2 = __attribute__((ext_vector_type(2))) _Float16;
using f32x4 = __attribute__((ext_vector_type(4))) float;

__device__ __forceinline__ float fast_exp2(float x) {
#if __has_builtin(__builtin_amdgcn_exp2f)
  return __builtin_amdgcn_exp2f(x);
#else
  return exp2f(x);
#endif
}
__device__ __forceinline__ float fast_rcp(float x) {
#if __has_builtin(__builtin_amdgcn_rcpf)
  return __builtin_amdgcn_rcpf(x);
#else
  return 1.0f / x;
#endif
}

// ---------------------------------------------------------------------------
// Prep: WT fp16 [2][128][512]; WT[s][n][k] = W_s[k][n]. 256 KB, L2-resident.
// ---------------------------------------------------------------------------
__global__ __launch_bounds__(256)
void prep_wT_kernel(const float* __restrict__ Wq, const float* __restrict__ Wk,
                    _Float16* __restrict__ wT) {
  const int idx = blockIdx.x * 256 + threadIdx.x;   // 0 .. 2*512*128-1
  const int n = idx & 127;
  const int k = (idx >> 7) & 511;
  const int s = idx >> 16;
  const float* W = s ? Wk : Wq;
  wT[((size_t)(s * NH + n)) * NDQ + k] = (_Float16)W[k * NH + n];
}

// ---------------------------------------------------------------------------
// Projections via fp16 MFMA, LDS-FREE, barrier-free.
// Wave = 16 rows x 32 cols (2 frags of 16x16), block = 4 waves (64 rows).
// Grid (160, 4): bx<32 -> Q (M=2048), else K (M=8192); by = n-quarter.
// vlen-skip: K-blocks whose 64 keys all lie >= vlen[b] return immediately.
// Epilogue: exp2(acc*2log2e); Q -> Eq fp32 row-major;
// K -> ekC16 fp16 [b][h/8][key][8] (8 h-values contiguous per key;
// saturation-correct: Ek inf -> rcp 0 = tanh->1; Ek 0 -> rcp 1 = tanh->-1).
// ---------------------------------------------------------------------------
__global__ __launch_bounds__(256)
void proj_mfma_kernel(const float* __restrict__ Q, const float* __restrict__ Kin,
                      const _Float16* __restrict__ wT, const int* __restrict__ vlen,
                      float* __restrict__ qp, _Float16* __restrict__ ekC16) {
  const int bx = blockIdx.x;
  const int nq = blockIdx.y;          // n-quarter: cols nq*32 .. nq*32+31
  const bool isQ = (bx < 32);
  const float* A = isQ ? Q : Kin;
  const int m0 = (isQ ? bx : bx - 32) * 64;
  const int sIdx = isQ ? 0 : 1;

  if (!isQ) {
    const int b = m0 >> 10;
    if ((m0 & 1023) >= vlen[b]) return;   // dead keys: never consumed unmasked
  }

  const int w = threadIdx.x >> 6, lane = threadIdx.x & 63;
  const int mrow = m0 + w * 16 + (lane & 15);
  const int kseg = (lane >> 4) * 8;

  const float* aBase = A + (size_t)mrow * NDQ + kseg;
  const _Float16* wt0 = wT + ((size_t)(sIdx * NH + nq * 32 +      (lane & 15))) * NDQ + kseg;
  const _Float16* wt1 = wT + ((size_t)(sIdx * NH + nq * 32 + 16 + (lane & 15))) * NDQ + kseg;

  f32x4 acc0 = {}, acc1 = {};
#pragma unroll 4
  for (int k0 = 0; k0 < NDQ; k0 += 32) {
    const float4 a0 = *(const float4*)&aBase[k0];
    const float4 a1 = *(const float4*)&aBase[k0 + 4];
    f16x8 af;
    af[0] = (_Float16)a0.x; af[1] = (_Float16)a0.y;
    af[2] = (_Float16)a0.z; af[3] = (_Float16)a0.w;
    af[4] = (_Float16)a1.x; af[5] = (_Float16)a1.y;
    af[6] = (_Float16)a1.z; af[7] = (_Float16)a1.w;
    const f16x8 b0 = *(const f16x8*)&wt0[k0];
    const f16x8 b1 = *(const f16x8*)&wt1[k0];
    acc0 = __builtin_amdgcn_mfma_f32_16x16x32_f16(af, b0, acc0, 0, 0, 0);
    acc1 = __builtin_amdgcn_mfma_f32_16x16x32_f16(af, b1, acc1, 0, 0, 0);
  }

  const int orow = m0 + w * 16 + (lane >> 4) * 4;   // + r
  const int col0 = nq * 32 + (lane & 15);           // frag0 col; frag1 = +16
  if (isQ) {
#pragma unroll
    for (int r = 0; r < 4; ++r) {
      qp[(size_t)(orow + r) * NH + col0]      = fast_exp2(acc0[r] * TANH_SCALE);
      qp[(size_t)(orow + r) * NH + col0 + 16] = fast_exp2(acc1[r] * TANH_SCALE);
    }
  } else {
#pragma unroll
    for (int r = 0; r < 4; ++r) {
      const int grow = orow + r;
      const int b = grow >> 10, key = grow & 1023;
      const int c0 = col0, c1 = col0 + 16;
      ekC16[(((size_t)b * 16 + (c0 >> 3)) * NLK + key) * 8 + (c0 & 7)] =
          (_Float16)fast_exp2(acc0[r] * TANH_SCALE);
      ekC16[(((size_t)b * 16 + (c1 >> 3)) * NLK + key) * 8 + (c1 & 7)] =
          (_Float16)fast_exp2(acc1[r] * TANH_SCALE);
    }
  }
}

// ---------------------------------------------------------------------------
// One key's full score contribution: burst-load the key's 128 h (fp16,
// 16x f16x8 = 64 VGPR, 16 loads in flight), then a PURE-COMPUTE loop whose
// only memory ops are wave-uniform q/w scalar loads (R5's 73%-busy pattern).
// ---------------------------------------------------------------------------
__device__ __forceinline__ void score_one_key(const _Float16* __restrict__ kbase,
                                              const float* __restrict__ qbase,
                                              const float* __restrict__ wv,
                                              float acc[4]) {
  f16x8 kr[16];
#pragma unroll
  for (int c = 0; c < 16; ++c)
    kr[c] = *(const f16x8*)&kbase[(size_t)c * NLK * 8];

#pragma unroll
  for (int c = 0; c < 16; ++c) {
    const float4 wa = *(const float4*)&wv[c * 8];        // uniform -> s_load
    const float4 wb = *(const float4*)&wv[c * 8 + 4];    // uniform -> s_load
    const float k0 = (float)kr[c][0], k1 = (float)kr[c][1];
    const float k2 = (float)kr[c][2], k3 = (float)kr[c][3];
    const float k4 = (float)kr[c][4], k5 = (float)kr[c][5];
    const float k6 = (float)kr[c][6], k7 = (float)kr[c][7];
#pragma unroll
    for (int qi = 0; qi < 4; ++qi) {
      const float4 qa = *(const float4*)&qbase[qi * NH + c * 8];      // uniform
      const float4 qb = *(const float4*)&qbase[qi * NH + c * 8 + 4];  // uniform
      float a = acc[qi];
      a = fmaf(wa.x, fast_rcp(fmaf(qa.x, k0, 1.0f)), a);
      a = fmaf(wa.y, fast_rcp(fmaf(qa.y, k1, 1.0f)), a);
      a = fmaf(wa.z, fast_rcp(fmaf(qa.z, k2, 1.0f)), a);
      a = fmaf(wa.w, fast_rcp(fmaf(qa.w, k3, 1.0f)), a);
      a = fmaf(wb.x, fast_rcp(fmaf(qb.x, k4, 1.0f)), a);
      a = fmaf(wb.y, fast_rcp(fmaf(qb.y, k5, 1.0f)), a);
      a = fmaf(wb.z, fast_rcp(fmaf(qb.z, k6, 1.0f)), a);
      a = fmaf(wb.w, fast_rcp(fmaf(qb.w, k7, 1.0f)), a);
      acc[qi] = a;
    }
  }
}

// ---------------------------------------------------------------------------
// FUSED scores + masked softmax -> fp16 attn, v22.
// Block = 512 thr = 8 waves (launch_bounds(512,4) -> VGPR cap 128, NO SPILL);
// wave w owns keys [w*128, w*128+128): lane handles key w*128+lane then
// key +64 SEQUENTIALLY, reusing the same 64 kr VGPRs (peak live ~100 VGPR).
// QR=4; grid (64, NBATCH). Per-key vlen skip. In-block softmax (8 waves).
//   score = Wsum - 2*sum_h w*rcp(1 + Eq*Ek); Wsum cancels in softmax.
// ---------------------------------------------------------------------------
__global__ __launch_bounds__(512, 4)
void scores_softmax_kernel(const float* __restrict__ qp, const _Float16* __restrict__ ekC16,
                           const float* __restrict__ wv, const int* __restrict__ vlen,
                           _Float16* __restrict__ attnH) {
  const int qg = blockIdx.x;            // q group (4 rows), 0..63
  const int b  = blockIdx.y;            // batch
  const int w = threadIdx.x >> 6;       // 0..7 -> key segment of 128
  const int lane = threadIdx.x & 63;
  const int keyA = w * 128 + lane;
  const int keyB = keyA + 64;

  __shared__ float redm[8][4];
  __shared__ float reds[8][4];

  const float* qbase = &qp[(size_t)(b * NLQ + qg * 4) * NH];
  const int VL = vlen[b];

  float accA[4] = {}, accB[4] = {};
  if (w * 128 < VL) {                   // wave-uniform: skip fully-masked segments
    score_one_key(ekC16 + ((size_t)b * 16 * NLK + keyA) * 8, qbase, wv, accA);
    if (w * 128 + 64 < VL)              // second 64-key half may also be dead
      score_one_key(ekC16 + ((size_t)b * 16 * NLK + keyB) * 8, qbase, wv, accB);
  }

  // finalize scores with mask
  float sA[4], sB[4];
#pragma unroll
  for (int qi = 0; qi < 4; ++qi) {
    sA[qi] = (keyA < VL) ? -2.0f * accA[qi] : NEGV;
    sB[qi] = (keyB < VL) ? -2.0f * accB[qi] : NEGV;
  }

  // wave-level max per q-row, then cross-wave via LDS
#pragma unroll
  for (int qi = 0; qi < 4; ++qi) {
    float m = fmaxf(sA[qi], sB[qi]);
#pragma unroll
    for (int off = 32; off > 0; off >>= 1) m = fmaxf(m, __shfl_xor(m, off));
    if (lane == 0) redm[w][qi] = m;
  }
  __syncthreads();
  float mg[4];
#pragma unroll
  for (int qi = 0; qi < 4; ++qi) {
    float m = redm[0][qi];
#pragma unroll
    for (int ww = 1; ww < 8; ++ww) m = fmaxf(m, redm[ww][qi]);
    mg[qi] = m;
  }

  // exp + wave sum + cross-wave sum
  float pA[4], pB[4];
#pragma unroll
  for (int qi = 0; qi < 4; ++qi) {
    pA[qi] = fast_exp2((sA[qi] - mg[qi]) * LOG2E);
    pB[qi] = fast_exp2((sB[qi] - mg[qi]) * LOG2E);
    float sum = pA[qi] + pB[qi];
#pragma unroll
    for (int off = 32; off > 0; off >>= 1) sum += __shfl_xor(sum, off);
    if (lane == 0) reds[w][qi] = sum;
  }
  __syncthreads();

#pragma unroll
  for (int qi = 0; qi < 4; ++qi) {
    float tot = reds[0][qi];
#pragma unroll
    for (int ww = 1; ww < 8; ++ww) tot += reds[ww][qi];
    const float inv = fast_rcp(tot);
    _Float16* arow = &attnH[(size_t)(b * NLQ + qg * 4 + qi) * NLK];
    arow[keyA] = (_Float16)(pA[qi] * inv);
    arow[keyB] = (_Float16)(pB[qi] * inv);
  }
}

// ---------------------------------------------------------------------------
// PV via fp16 MFMA: out[b] = attn[b] (256x1024 fp16) @ V[b].
// Tile M64 x N32 -> grid (4,16,8) = 512 blocks = 2 blocks/CU.
// Block 256 thr = 4 waves; K-step 32, register prefetch. vlen-adaptive:
// attn==0 for keys>=VL, K-loop stops at ceil(VL/32)*32.
// ---------------------------------------------------------------------------
__global__ __launch_bounds__(256)
void pv_mfma_kernel(const _Float16* __restrict__ attnH, const float* __restrict__ V,
                    const int* __restrict__ vlen, float* __restrict__ out) {
  const int b  = blockIdx.z;
  const int m0 = blockIdx.x * 64;
  const int n0 = blockIdx.y * 32;
  const int tid = threadIdx.x;
  const int w = tid >> 6, lane = tid & 63;
  const int kmax = (vlen[b] + 31) & ~31;   // ceil to K-step; >=32 since VL>=1

  __shared__ _Float16 aT[64][40];   // [m][k]
  __shared__ _Float16 vT[32][32];   // [n][k], swizzled

  const _Float16* aBase = attnH + (size_t)(b * NLQ + m0) * NLK;
  const float*    vBase = V + (size_t)b * NLK * NDV + n0;
  float*          oBase = out + (size_t)(b * NLQ + m0) * NDV + n0;

  const int ar = tid >> 2;               // 0..63
  const int ak = (tid & 3) * 8;          // 0,8,16,24
  const int vk = tid >> 3;               // 0..31 (k within tile)
  const int vn = (tid & 7) * 4;          // 0..28 (n within tile)
  const int vswz = ((vn >> 2) & 3) << 3;

  const int am  = w * 16 + (lane & 15);
  const int akf = (lane >> 4) * 8;
  const int bn  = lane & 15;
  const int bks = akf ^ (((bn >> 2) & 3) << 3);

  f32x4 acc0 = {}, acc1 = {};

  // prologue: prefetch tile 0 into registers
  f16x8 aReg = *(const f16x8*)&aBase[(size_t)ar * NLK + ak];
  float4 vReg = *(const float4*)&vBase[(size_t)vk * NDV + vn];

  for (int k0 = 0; k0 < kmax; k0 += 32) {
    __syncthreads();   // previous tile's LDS reads complete
    *(f16x8*)&aT[ar][ak] = aReg;
    {
      const int ks = vk ^ vswz;
      vT[vn + 0][ks] = (_Float16)vReg.x;
      vT[vn + 1][ks] = (_Float16)vReg.y;
      vT[vn + 2][ks] = (_Float16)vReg.z;
      vT[vn + 3][ks] = (_Float16)vReg.w;
    }
    __syncthreads();

    // prefetch NEXT tile while current MFMAs run
    if (k0 + 32 < kmax) {
      aReg = *(const f16x8*)&aBase[(size_t)ar * NLK + k0 + 32 + ak];
      vReg = *(const float4*)&vBase[(size_t)(k0 + 32 + vk) * NDV + vn];
    }

    const f16x8 af = *(const f16x8*)&aT[am][akf];
    const f16x8 bf0 = *(const f16x8*)&vT[ 0 + bn][bks];
    const f16x8 bf1 = *(const f16x8*)&vT[16 + bn][bks];
    acc0 = __builtin_amdgcn_mfma_f32_16x16x32_f16(af, bf0, acc0, 0, 0, 0);
    acc1 = __builtin_amdgcn_mfma_f32_16x16x32_f16(af, bf1, acc1, 0, 0, 0);
  }

  const int orow = w * 16 + (lane >> 4) * 4;
  const int ocol = lane & 15;
#pragma unroll
  for (int r = 0; r < 4; ++r) {
    oBase[(size_t)(orow + r) * NDV + ocol +  0] = acc0[r];
    oBase[(size_t)(orow + r) * NDV + ocol + 16] = acc1[r];
  }
}

// ---------------------------------------------------------------------------
extern "C" void kernel_launch(void* const* d_in, const int* in_sizes, int n_in,
                              void* d_out, int out_size, void* d_ws, size_t ws_size,
                              hipStream_t stream) {
  const float* Q    = (const float*)d_in[0];
  const float* Kin  = (const float*)d_in[1];
  const float* V    = (const float*)d_in[2];
  const int*   vlen = (const int*)d_in[3];
  const float* Wq   = (const float*)d_in[4];
  const float* Wk   = (const float*)d_in[5];
  const float* wv   = (const float*)d_in[6];
  float* out = (float*)d_out;

  float* qp = (float*)d_ws;                               // Eq fp32: 2048*128
  _Float16* ekC16 = (_Float16*)(qp + NBATCH * NLQ * NH);  // fp16: 8*16*1024*8
  _Float16* attnH = ekC16 + (size_t)NBATCH * NH * NLK;    // fp16: 8*256*1024
  _Float16* wT = attnH + (size_t)NBATCH * NLQ * NLK;      // fp16: 2*128*512

  hipLaunchKernelGGL(prep_wT_kernel, dim3(2 * NDQ * NH / 256), dim3(256), 0, stream,
                     Wq, Wk, wT);
  hipLaunchKernelGGL(proj_mfma_kernel, dim3(160, 4), dim3(256), 0, stream,
                     Q, Kin, wT, vlen, qp, ekC16);
  hipLaunchKernelGGL(scores_softmax_kernel, dim3(64, NBATCH), dim3(512), 0, stream,
                     qp, ekC16, wv, vlen, attnH);
  hipLaunchKernelGGL(pv_mfma_kernel, dim3(NLQ / 64, NDV / 32, NBATCH), dim3(256), 0, stream,
                     attnH, V, vlen, out);
}

// Round 23
// 73.804 us; speedup vs baseline: 4.7203x; 2.8204x over previous
//
#include <hip/hip_runtime.h>

// Problem constants
#define NBATCH 8
#define NLQ    256
#define NLK    1024
#define NDQ    512
#define NDV    512
#define NH     128
#define NEGV   -1000000.0f
#define TANH_SCALE 2.8853900817779268f   // 2*log2(e)
#define LOG2E      1.4426950408889634f

using f16x8 = __attribute__((ext_vector_type(8))) _Float16;
using f16x4 = __attribute__((ext_vector_type(4))) _Float16;
using f16x2 = __attribute__((ext_vector_type(2))) _Float16;
using f32x4 = __attribute__((ext_vector_type(4))) float;

__device__ __forceinline__ float fast_exp2(float x) {
#if __has_builtin(__builtin_amdgcn_exp2f)
  return __builtin_amdgcn_exp2f(x);
#else
  return exp2f(x);
#endif
}
__device__ __forceinline__ float fast_rcp(float x) {
#if __has_builtin(__builtin_amdgcn_rcpf)
  return __builtin_amdgcn_rcpf(x);
#else
  return 1.0f / x;
#endif
}

// ---------------------------------------------------------------------------
// Prep: WT fp16 [2][128][512]; WT[s][n][k] = W_s[k][n]. 256 KB, L2-resident.
// ---------------------------------------------------------------------------
__global__ __launch_bounds__(256)
void prep_wT_kernel(const float* __restrict__ Wq, const float* __restrict__ Wk,
                    _Float16* __restrict__ wT) {
  const int idx = blockIdx.x * 256 + threadIdx.x;   // 0 .. 2*512*128-1
  const int n = idx & 127;
  const int k = (idx >> 7) & 511;
  const int s = idx >> 16;
  const float* W = s ? Wk : Wq;
  wT[((size_t)(s * NH + n)) * NDQ + k] = (_Float16)W[k * NH + n];
}

// ---------------------------------------------------------------------------
// Projections via fp16 MFMA, LDS-FREE, barrier-free.
// Wave = 16 rows x 32 cols (2 frags of 16x16), block = 4 waves (64 rows).
// Grid (160, 4): bx<32 -> Q (M=2048), else K (M=8192); by = n-quarter.
// vlen-skip: K-blocks whose 64 keys all lie >= vlen[b] return immediately.
// Epilogue: exp2(acc*2log2e); Q -> Eq fp32 row-major, K -> EkT[b][h][key].
// ---------------------------------------------------------------------------
__global__ __launch_bounds__(256)
void proj_mfma_kernel(const float* __restrict__ Q, const float* __restrict__ Kin,
                      const _Float16* __restrict__ wT, const int* __restrict__ vlen,
                      float* __restrict__ qp, float* __restrict__ ekT) {
  const int bx = blockIdx.x;
  const int nq = blockIdx.y;          // n-quarter: cols nq*32 .. nq*32+31
  const bool isQ = (bx < 32);
  const float* A = isQ ? Q : Kin;
  const int m0 = (isQ ? bx : bx - 32) * 64;
  const int sIdx = isQ ? 0 : 1;

  if (!isQ) {
    const int b = m0 >> 10;
    if ((m0 & 1023) >= vlen[b]) return;   // dead keys: never consumed unmasked
  }

  const int w = threadIdx.x >> 6, lane = threadIdx.x & 63;
  const int mrow = m0 + w * 16 + (lane & 15);
  const int kseg = (lane >> 4) * 8;

  const float* aBase = A + (size_t)mrow * NDQ + kseg;
  const _Float16* wt0 = wT + ((size_t)(sIdx * NH + nq * 32 +      (lane & 15))) * NDQ + kseg;
  const _Float16* wt1 = wT + ((size_t)(sIdx * NH + nq * 32 + 16 + (lane & 15))) * NDQ + kseg;

  f32x4 acc0 = {}, acc1 = {};
#pragma unroll 4
  for (int k0 = 0; k0 < NDQ; k0 += 32) {
    const float4 a0 = *(const float4*)&aBase[k0];
    const float4 a1 = *(const float4*)&aBase[k0 + 4];
    f16x8 af;
    af[0] = (_Float16)a0.x; af[1] = (_Float16)a0.y;
    af[2] = (_Float16)a0.z; af[3] = (_Float16)a0.w;
    af[4] = (_Float16)a1.x; af[5] = (_Float16)a1.y;
    af[6] = (_Float16)a1.z; af[7] = (_Float16)a1.w;
    const f16x8 b0 = *(const f16x8*)&wt0[k0];
    const f16x8 b1 = *(const f16x8*)&wt1[k0];
    acc0 = __builtin_amdgcn_mfma_f32_16x16x32_f16(af, b0, acc0, 0, 0, 0);
    acc1 = __builtin_amdgcn_mfma_f32_16x16x32_f16(af, b1, acc1, 0, 0, 0);
  }

  const int orow = m0 + w * 16 + (lane >> 4) * 4;   // + r
  const int col0 = nq * 32 + (lane & 15);           // frag0 col; frag1 = +16
  if (isQ) {
#pragma unroll
    for (int r = 0; r < 4; ++r) {
      qp[(size_t)(orow + r) * NH + col0]      = fast_exp2(acc0[r] * TANH_SCALE);
      qp[(size_t)(orow + r) * NH + col0 + 16] = fast_exp2(acc1[r] * TANH_SCALE);
    }
  } else {
#pragma unroll
    for (int r = 0; r < 4; ++r) {
      const int grow = orow + r;
      const int b = grow >> 10, key = grow & 1023;
      ekT[((size_t)(b * NH) + col0)      * NLK + key] = fast_exp2(acc0[r] * TANH_SCALE);
      ekT[((size_t)(b * NH) + col0 + 16) * NLK + key] = fast_exp2(acc1[r] * TANH_SCALE);
    }
  }
}

// ---------------------------------------------------------------------------
// FUSED scores + masked softmax -> fp16 attn (R16 structure) + vlen skip
// + ping-pong kv pipeline: g-loop unrolled x2 with alternating register
// sets kvA/kvB -> 8 loads in flight, zero copy-moves. (Best measured: R18.)
//   score = Wsum - 2*sum_h w*rcp(1 + Eq*Ek); Wsum cancels in softmax.
// ---------------------------------------------------------------------------
__global__ __launch_bounds__(512)
void scores_softmax_kernel(const float* __restrict__ qp, const float* __restrict__ ekT,
                           const float* __restrict__ wv, const int* __restrict__ vlen,
                           _Float16* __restrict__ attnH) {
  const int qg = blockIdx.x;            // q group (4 rows), 0..63
  const int b  = blockIdx.y;            // batch
  const int w = threadIdx.x >> 6;       // 0..7 -> key segment of 128
  const int lane = threadIdx.x & 63;
  const int key0 = w * 128 + lane * 2;

  __shared__ float redm[8][4];
  __shared__ float reds[8][4];

  const float* kcol  = &ekT[(size_t)b * NH * NLK + key0];       // + h*NLK
  const float* qbase = &qp[(size_t)(b * NLQ + qg * 4) * NH];
  const int VL = vlen[b];

  float2 acc[4] = {};
  if (w * 128 < VL) {                   // wave-uniform: skip fully-masked segments
    float2 kvA[4], kvB[4];
#pragma unroll
    for (int hh = 0; hh < 4; ++hh)
      kvA[hh] = *(const float2*)&kcol[(size_t)hh * NLK];

#pragma unroll
    for (int g = 0; g < 32; g += 2) {
      // stage B: load g+1's kv while g's math runs
#pragma unroll
      for (int hh = 0; hh < 4; ++hh)
        kvB[hh] = *(const float2*)&kcol[(size_t)((g + 1) * 4 + hh) * NLK];

      {
        const float4 w4 = *(const float4*)&wv[g * 4];               // uniform
        float4 q4[4];
#pragma unroll
        for (int qi = 0; qi < 4; ++qi)
          q4[qi] = *(const float4*)&qbase[qi * NH + g * 4];         // uniform
#pragma unroll
        for (int hh = 0; hh < 4; ++hh) {
          const float2 kv = kvA[hh];
          const float wl = (hh == 0) ? w4.x : (hh == 1) ? w4.y : (hh == 2) ? w4.z : w4.w;
#pragma unroll
          for (int qi = 0; qi < 4; ++qi) {
            const float qs = (hh == 0) ? q4[qi].x : (hh == 1) ? q4[qi].y
                           : (hh == 2) ? q4[qi].z : q4[qi].w;
            acc[qi].x = fmaf(wl, fast_rcp(fmaf(qs, kv.x, 1.0f)), acc[qi].x);
            acc[qi].y = fmaf(wl, fast_rcp(fmaf(qs, kv.y, 1.0f)), acc[qi].y);
          }
        }
      }

      // stage A: load g+2's kv while g+1's math runs
      if (g + 2 < 32) {
#pragma unroll
        for (int hh = 0; hh < 4; ++hh)
          kvA[hh] = *(const float2*)&kcol[(size_t)((g + 2) * 4 + hh) * NLK];
      }

      {
        const float4 w4 = *(const float4*)&wv[(g + 1) * 4];         // uniform
        float4 q4[4];
#pragma unroll
        for (int qi = 0; qi < 4; ++qi)
          q4[qi] = *(const float4*)&qbase[qi * NH + (g + 1) * 4];   // uniform
#pragma unroll
        for (int hh = 0; hh < 4; ++hh) {
          const float2 kv = kvB[hh];
          const float wl = (hh == 0) ? w4.x : (hh == 1) ? w4.y : (hh == 2) ? w4.z : w4.w;
#pragma unroll
          for (int qi = 0; qi < 4; ++qi) {
            const float qs = (hh == 0) ? q4[qi].x : (hh == 1) ? q4[qi].y
                           : (hh == 2) ? q4[qi].z : q4[qi].w;
            acc[qi].x = fmaf(wl, fast_rcp(fmaf(qs, kv.x, 1.0f)), acc[qi].x);
            acc[qi].y = fmaf(wl, fast_rcp(fmaf(qs, kv.y, 1.0f)), acc[qi].y);
          }
        }
      }
    }
  }

  // finalize scores with mask
  float2 s[4];
#pragma unroll
  for (int qi = 0; qi < 4; ++qi) {
    s[qi].x = (key0 + 0 < VL) ? -2.0f * acc[qi].x : NEGV;
    s[qi].y = (key0 + 1 < VL) ? -2.0f * acc[qi].y : NEGV;
  }

  // wave-level max per q-row, then cross-wave via LDS
#pragma unroll
  for (int qi = 0; qi < 4; ++qi) {
    float m = fmaxf(s[qi].x, s[qi].y);
#pragma unroll
    for (int off = 32; off > 0; off >>= 1) m = fmaxf(m, __shfl_xor(m, off));
    if (lane == 0) redm[w][qi] = m;
  }
  __syncthreads();
  float mg[4];
#pragma unroll
  for (int qi = 0; qi < 4; ++qi) {
    float m = redm[0][qi];
#pragma unroll
    for (int ww = 1; ww < 8; ++ww) m = fmaxf(m, redm[ww][qi]);
    mg[qi] = m;
  }

  // exp + wave sum + cross-wave sum
  float2 p[4];
#pragma unroll
  for (int qi = 0; qi < 4; ++qi) {
    p[qi].x = fast_exp2((s[qi].x - mg[qi]) * LOG2E);
    p[qi].y = fast_exp2((s[qi].y - mg[qi]) * LOG2E);
    float sum = p[qi].x + p[qi].y;
#pragma unroll
    for (int off = 32; off > 0; off >>= 1) sum += __shfl_xor(sum, off);
    if (lane == 0) reds[w][qi] = sum;
  }
  __syncthreads();

#pragma unroll
  for (int qi = 0; qi < 4; ++qi) {
    float tot = reds[0][qi];
#pragma unroll
    for (int ww = 1; ww < 8; ++ww) tot += reds[ww][qi];
    const float inv = fast_rcp(tot);
    f16x2 h;
    h[0] = (_Float16)(p[qi].x * inv);
    h[1] = (_Float16)(p[qi].y * inv);
    *(f16x2*)&attnH[(size_t)(b * NLQ + qg * 4 + qi) * NLK + key0] = h;
  }
}

// ---------------------------------------------------------------------------
// PV via fp16 MFMA: out[b] = attn[b] (256x1024 fp16) @ V[b].
// Tile M64 x N32 -> grid (4,16,8) = 512 blocks = 2 blocks/CU.
// Block 256 thr = 4 waves; K-step 32, register prefetch. vlen-adaptive:
// attn==0 for keys>=VL, K-loop stops at ceil(VL/32)*32.
// ---------------------------------------------------------------------------
__global__ __launch_bounds__(256)
void pv_mfma_kernel(const _Float16* __restrict__ attnH, const float* __restrict__ V,
                    const int* __restrict__ vlen, float* __restrict__ out) {
  const int b  = blockIdx.z;
  const int m0 = blockIdx.x * 64;
  const int n0 = blockIdx.y * 32;
  const int tid = threadIdx.x;
  const int w = tid >> 6, lane = tid & 63;
  const int kmax = (vlen[b] + 31) & ~31;   // ceil to K-step; >=32 since VL>=1

  __shared__ _Float16 aT[64][40];   // [m][k]
  __shared__ _Float16 vT[32][32];   // [n][k], swizzled

  const _Float16* aBase = attnH + (size_t)(b * NLQ + m0) * NLK;
  const float*    vBase = V + (size_t)b * NLK * NDV + n0;
  float*          oBase = out + (size_t)(b * NLQ + m0) * NDV + n0;

  const int ar = tid >> 2;               // 0..63
  const int ak = (tid & 3) * 8;          // 0,8,16,24
  const int vk = tid >> 3;               // 0..31 (k within tile)
  const int vn = (tid & 7) * 4;          // 0..28 (n within tile)
  const int vswz = ((vn >> 2) & 3) << 3;

  const int am  = w * 16 + (lane & 15);
  const int akf = (lane >> 4) * 8;
  const int bn  = lane & 15;
  const int bks = akf ^ (((bn >> 2) & 3) << 3);

  f32x4 acc0 = {}, acc1 = {};

  // prologue: prefetch tile 0 into registers
  f16x8 aReg = *(const f16x8*)&aBase[(size_t)ar * NLK + ak];
  float4 vReg = *(const float4*)&vBase[(size_t)vk * NDV + vn];

  for (int k0 = 0; k0 < kmax; k0 += 32) {
    __syncthreads();   // previous tile's LDS reads complete
    *(f16x8*)&aT[ar][ak] = aReg;
    {
      const int ks = vk ^ vswz;
      vT[vn + 0][ks] = (_Float16)vReg.x;
      vT[vn + 1][ks] = (_Float16)vReg.y;
      vT[vn + 2][ks] = (_Float16)vReg.z;
      vT[vn + 3][ks] = (_Float16)vReg.w;
    }
    __syncthreads();

    // prefetch NEXT tile while current MFMAs run
    if (k0 + 32 < kmax) {
      aReg = *(const f16x8*)&aBase[(size_t)ar * NLK + k0 + 32 + ak];
      vReg = *(const float4*)&vBase[(size_t)(k0 + 32 + vk) * NDV + vn];
    }

    const f16x8 af = *(const f16x8*)&aT[am][akf];
    const f16x8 bf0 = *(const f16x8*)&vT[ 0 + bn][bks];
    const f16x8 bf1 = *(const f16x8*)&vT[16 + bn][bks];
    acc0 = __builtin_amdgcn_mfma_f32_16x16x32_f16(af, bf0, acc0, 0, 0, 0);
    acc1 = __builtin_amdgcn_mfma_f32_16x16x32_f16(af, bf1, acc1, 0, 0, 0);
  }

  const int orow = w * 16 + (lane >> 4) * 4;
  const int ocol = lane & 15;
#pragma unroll
  for (int r = 0; r < 4; ++r) {
    oBase[(size_t)(orow + r) * NDV + ocol +  0] = acc0[r];
    oBase[(size_t)(orow + r) * NDV + ocol + 16] = acc1[r];
  }
}

// ---------------------------------------------------------------------------
extern "C" void kernel_launch(void* const* d_in, const int* in_sizes, int n_in,
                              void* d_out, int out_size, void* d_ws, size_t ws_size,
                              hipStream_t stream) {
  const float* Q    = (const float*)d_in[0];
  const float* Kin  = (const float*)d_in[1];
  const float* V    = (const float*)d_in[2];
  const int*   vlen = (const int*)d_in[3];
  const float* Wq   = (const float*)d_in[4];
  const float* Wk   = (const float*)d_in[5];
  const float* wv   = (const float*)d_in[6];
  float* out = (float*)d_out;

  float* qp  = (float*)d_ws;                    // Eq: 2048*128 row-major
  float* ekT = qp + NBATCH * NLQ * NH;          // EkT: 8*128*1024
  _Float16* attnH = (_Float16*)(ekT + NBATCH * NH * NLK);       // 8*256*1024 fp16
  _Float16* wT = attnH + (size_t)NBATCH * NLQ * NLK;            // 2*128*512 fp16

  hipLaunchKernelGGL(prep_wT_kernel, dim3(2 * NDQ * NH / 256), dim3(256), 0, stream,
                     Wq, Wk, wT);
  hipLaunchKernelGGL(proj_mfma_kernel, dim3(160, 4), dim3(256), 0, stream,
                     Q, Kin, wT, vlen, qp, ekT);
  hipLaunchKernelGGL(scores_softmax_kernel, dim3(64, NBATCH), dim3(512), 0, stream,
                     qp, ekT, wv, vlen, attnH);
  hipLaunchKernelGGL(pv_mfma_kernel, dim3(NLQ / 64, NDV / 32, NBATCH), dim3(256), 0, stream,
                     attnH, V, vlen, out);
}